// Round 6
// baseline (335.192 us; speedup 1.0000x reference)
//
#include <hip/hip_runtime.h>
#include <hip/hip_cooperative_groups.h>

// Problem constants (fixed by setup_inputs)
#define NB 16        // graphs
#define NN 256       // nodes per graph
#define ND 64        // emb dim
#define NE (16*4096) // total edges
#define NNODE (NB*NN)          // 4096 global rows
#define MASK_WORDS (NNODE*8)   // 256-bit column mask per row = 32768 words (128 KB)

#define GRID 2048
#define BLK  256
#define NTHREADS (GRID*BLK)    // 524288

typedef float f4 __attribute__((ext_vector_type(4)));

namespace cg = cooperative_groups;

// One cooperative dispatch:
//  A: zero mask (plain stores)
//  B: atomicOr edge bits into mask (device-scope atomicOr)
//  C: edge-row copies (disjoint cells) interleaved with masked streaming fill
//     (mask via PLAIN loads — L1-cacheable; grid.sync provides visibility)
__global__ __launch_bounds__(BLK) void fused_coop(const float* __restrict__ edge_attr,
                                                  const int* __restrict__ edge_index,
                                                  const float* __restrict__ emb,
                                                  unsigned* __restrict__ mask,
                                                  f4* __restrict__ out) {
    const int tid = blockIdx.x * BLK + threadIdx.x;
    cg::grid_group grid = cg::this_grid();

    // ---- A: zero the mask (plain stores; grid.sync release makes them visible)
    if (tid < MASK_WORDS) mask[tid] = 0u;
    grid.sync();

    // ---- B: scatter edge presence bits
    if (tid < NE) {
        const int src = edge_index[tid];                 // global row (= g*256 + ls)
        const int ld  = edge_index[NE + tid] & (NN - 1); // local col
        atomicOr(&mask[src * 8 + (ld >> 5)], 1u << (ld & 31));
    }
    grid.sync();

    // ---- C1: edge-row copies (write set = edge cells, disjoint from C2)
    #pragma unroll
    for (int k = 0; k < (NE * 16) / NTHREADS; ++k) {     // 2
        const int t = tid + k * NTHREADS;
        const int e = t >> 4;
        const int q = t & 15;
        const int src = edge_index[e];
        const int ld  = edge_index[NE + e] & (NN - 1);
        out[((long)src * NN + ld) * (ND / 4) + q] =
            ((const f4*)edge_attr)[(long)e * (ND / 4) + q];
    }

    // ---- C2: streaming fill of all NON-edge cells.
    // Per-thread: col and f4-slot are loop-invariant (stride cells % 256 == 0).
    const int dq = tid & (ND / 4 - 1);                   // f4 slot in row
    const f4 v1 = ((const f4*)(emb + 1 * ND))[dq];       // diagonal
    const f4 v2 = ((const f4*)(emb + 2 * ND))[dq];       // disconnected
    const int c0   = tid >> 4;                           // starting cell
    const int col  = c0 & (NN - 1);                      // loop-invariant column
    const int slot = col >> 5;
    const unsigned bit = 1u << (col & 31);
    constexpr int iters = NB * NN * NN * (ND / 4) / NTHREADS;  // 32
    constexpr int cell_stride = NTHREADS / 16;                 // 32768 cells/iter
    #pragma unroll 8
    for (int it = 0; it < iters; ++it) {
        const int c  = c0 + it * cell_stride;
        const int ig = c >> 8;                           // global row
        const unsigned m = mask[ig * 8 + slot];          // plain load -> L1
        if (!(m & bit)) {
            out[(long)c * (ND / 4) + dq] = ((ig & (NN - 1)) == col) ? v1 : v2;
        }
    }
}

extern "C" void kernel_launch(void* const* d_in, const int* in_sizes, int n_in,
                              void* d_out, int out_size, void* d_ws, size_t ws_size,
                              hipStream_t stream) {
    const float* edge_attr  = (const float*)d_in[0];
    const float* emb_table  = (const float*)d_in[1];
    const int*   edge_index = (const int*)d_in[2];
    // d_in[3] = batch_vec — unused (indices derivable from src/dst bit math)
    f4*       out  = (f4*)d_out;
    unsigned* mask = (unsigned*)d_ws;   // 128 KB of the workspace

    void* args[] = {(void*)&edge_attr, (void*)&edge_index, (void*)&emb_table,
                    (void*)&mask, (void*)&out};
    hipLaunchCooperativeKernel((void*)fused_coop, dim3(GRID), dim3(BLK), args, 0, stream);
}

// Round 7
// 67.453 us; speedup vs baseline: 4.9692x; 4.9692x over previous
//
#include <hip/hip_runtime.h>

// Problem constants (fixed by setup_inputs)
#define NB 16        // graphs
#define NN 256       // nodes per graph
#define ND 64        // emb dim
#define NE (16*4096) // total edges
#define NNODE (NB*NN)            // 4096 global rows
#define MAP_CELLS (NNODE*NN)     // 1,048,576 cells (4 MB as int)

#define GRID 2048
#define BLK  256
#define NTHREADS (GRID*BLK)      // 524288 threads -> 32768 cells/iter

typedef float f4 __attribute__((ext_vector_type(4)));

// Scatter edge ids into the dense cell map. Cells are unique per edge -> plain stores.
__global__ __launch_bounds__(256) void scatter_kernel(const int* __restrict__ edge_index,
                                                      int* __restrict__ map) {
    const int e = blockIdx.x * 256 + threadIdx.x;
    if (e >= NE) return;
    const int src = edge_index[e];                 // global row (= g*256 + ls)
    const int ld  = edge_index[NE + e] & (NN - 1); // local col
    map[src * NN + ld] = e;
}

// Single full-stream writer: out[cell] = attr[id] if id>=0 else (diag ? v1 : v2).
// 16 lanes per cell, one f4 each; stores are unconditional and fully sequential.
__global__ __launch_bounds__(BLK) void main_kernel(const float* __restrict__ edge_attr,
                                                   const float* __restrict__ emb,
                                                   const int* __restrict__ map,
                                                   f4* __restrict__ out) {
    const int tid = blockIdx.x * BLK + threadIdx.x;
    const int dq  = tid & (ND / 4 - 1);                 // f4 slot in row (invariant)
    const f4 v1 = ((const f4*)(emb + 1 * ND))[dq];      // diagonal
    const f4 v2 = ((const f4*)(emb + 2 * ND))[dq];      // disconnected
    const int c0  = tid >> 4;                           // starting cell
    const int col = c0 & (NN - 1);                      // loop-invariant column
    constexpr int iters = MAP_CELLS / (NTHREADS / 16);  // 32
    constexpr int cell_stride = NTHREADS / 16;          // 32768
    #pragma unroll 4
    for (int it = 0; it < iters; ++it) {
        const int c  = c0 + it * cell_stride;
        const int ig = c >> 8;                          // global row
        const int id = map[c];                          // broadcast across the 16 lanes
        f4 v;
        if (id >= 0) {
            v = ((const f4*)edge_attr)[(long)id * (ND / 4) + dq];
        } else {
            v = ((ig & (NN - 1)) == col) ? v1 : v2;
        }
        out[(long)c * (ND / 4) + dq] = v;
    }
}

extern "C" void kernel_launch(void* const* d_in, const int* in_sizes, int n_in,
                              void* d_out, int out_size, void* d_ws, size_t ws_size,
                              hipStream_t stream) {
    const float* edge_attr  = (const float*)d_in[0];
    const float* emb_table  = (const float*)d_in[1];
    const int*   edge_index = (const int*)d_in[2];
    // d_in[3] = batch_vec — unused (indices derivable from src/dst bit math)
    f4*  out = (f4*)d_out;
    int* map = (int*)d_ws;   // 4 MB of the workspace

    hipMemsetAsync(map, 0xFF, MAP_CELLS * sizeof(int), stream);   // all cells -> -1
    scatter_kernel<<<NE / 256, 256, 0, stream>>>(edge_index, map);
    main_kernel<<<GRID, BLK, 0, stream>>>(edge_attr, emb_table, map, out);
}

// Round 8
// 58.623 us; speedup vs baseline: 5.7178x; 1.1506x over previous
//
#include <hip/hip_runtime.h>

// Problem constants (fixed by setup_inputs)
#define NB 16        // graphs
#define NN 256       // nodes per graph
#define ND 64        // emb dim
#define NE (16*4096) // total edges
#define NNODE (NB*NN)          // 4096 global rows
#define MASK_WORDS (NNODE*8)   // 256-bit column mask per row = 32768 words (128 KB)

#define EDGE_BLOCKS 4096       // NE*16 lanes / 256
#define FILL_BLOCKS NNODE      // one block per output row

typedef float f4 __attribute__((ext_vector_type(4)));

// Scatter edge presence bits: mask[src][col/32] |= 1<<(col%32). 128 KB, L2-resident.
__global__ __launch_bounds__(256) void mask_kernel(const int* __restrict__ edge_index,
                                                   unsigned* __restrict__ mask) {
    const int e = blockIdx.x * 256 + threadIdx.x;
    if (e >= NE) return;
    const int src = edge_index[e];                 // global row (= g*256 + ls)
    const int ld  = edge_index[NE + e] & (NN - 1); // local col
    atomicOr(&mask[src * 8 + (ld >> 5)], 1u << (ld & 31));
}

// One dispatch, two disjoint jobs (block-ordered: edge blocks launch first):
//  blocks [0, EDGE_BLOCKS):   copy edge_attr rows to their dense cells
//  blocks [EDGE_BLOCKS, ...): per-ROW masked fill. Row mask (8 words) loaded
//  once via scalar loads; inner loop = pure contiguous stores, no vector loads.
__global__ __launch_bounds__(256) void fused_kernel(const float* __restrict__ edge_attr,
                                                    const int* __restrict__ edge_index,
                                                    const float* __restrict__ emb,
                                                    const unsigned* __restrict__ mask,
                                                    f4* __restrict__ out) {
    if (blockIdx.x < EDGE_BLOCKS) {
        // 16 lanes per edge, one f4 each (contiguous 256 B per edge cell)
        const int t = blockIdx.x * 256 + threadIdx.x;
        const int e = t >> 4;
        const int q = t & 15;
        const int src = edge_index[e];
        const int ld  = edge_index[NE + e] & (NN - 1);
        out[((long)src * NN + ld) * (ND / 4) + q] =
            ((const f4*)edge_attr)[(long)e * (ND / 4) + q];
        return;
    }

    // ---- per-row fill: block handles one full row (256 cells = 64 KB contiguous)
    const int row  = blockIdx.x - EDGE_BLOCKS;     // 0..4095, wave-uniform
    const int diag = row & (NN - 1);               // diagonal column of this row
    const unsigned* __restrict__ mrow = mask + row * 8;
    unsigned w[8];
    #pragma unroll
    for (int k = 0; k < 8; ++k) w[k] = mrow[k];    // uniform address -> scalar loads

    const int ci = threadIdx.x >> 4;               // cell within pass, 0..15
    const int dq = threadIdx.x & 15;               // f4 slot within cell
    const f4 v1 = ((const f4*)(emb + 1 * ND))[dq]; // diagonal
    const f4 v2 = ((const f4*)(emb + 2 * ND))[dq]; // disconnected
    f4* __restrict__ rowout = out + (long)row * NN * (ND / 4);

    #pragma unroll
    for (int pass = 0; pass < 16; ++pass) {        // block writes 4 KB contiguous per pass
        const int col = pass * 16 + ci;
        const unsigned bits = w[pass >> 1] >> ((pass & 1) * 16);  // compile-time word idx
        if (!((bits >> ci) & 1u)) {                // skip edge cells (disjoint from edge job)
            rowout[col * (ND / 4) + dq] = (col == diag) ? v1 : v2;
        }
    }
}

extern "C" void kernel_launch(void* const* d_in, const int* in_sizes, int n_in,
                              void* d_out, int out_size, void* d_ws, size_t ws_size,
                              hipStream_t stream) {
    const float* edge_attr  = (const float*)d_in[0];
    const float* emb_table  = (const float*)d_in[1];
    const int*   edge_index = (const int*)d_in[2];
    // d_in[3] = batch_vec — unused (indices derivable from src/dst bit math)
    f4*       out  = (f4*)d_out;
    unsigned* mask = (unsigned*)d_ws;   // 128 KB of the workspace

    hipMemsetAsync(mask, 0, MASK_WORDS * sizeof(unsigned), stream);  // capture-safe
    mask_kernel<<<NE / 256, 256, 0, stream>>>(edge_index, mask);
    fused_kernel<<<EDGE_BLOCKS + FILL_BLOCKS, 256, 0, stream>>>(
        edge_attr, edge_index, emb_table, mask, out);
}